// Round 10
// baseline (2680.540 us; speedup 1.0000x reference)
//
#include <hip/hip_runtime.h>
#include <stdint.h>

typedef unsigned int u32;
typedef unsigned short u16;

#define NB   2048
#define SS   256
#define HH   64
#define VV   4
#define LATD 3
#define NTHR 512   // 8 waves, wave = 1 batch row, 256 blocks = 1 block/CU, 2 waves/SIMD

// float-element offsets in d_out: recons [B,S,1,V], tokens [B,S], mu, log_var
#define TOK_OFF (NB*SS*VV)
#define MU_OFF  (TOK_OFF + NB*SS)
#define LV_OFF  (MU_OFF + NB*LATD)

// ---------- JAX threefry2x32 (20 rounds, explicit) ----------
__device__ __forceinline__ void tf2x32(u32 k0, u32 k1, u32 x0, u32 x1, u32& o0, u32& o1){
  u32 k2 = k0 ^ k1 ^ 0x1BD11BDAu;
  x0 += k0; x1 += k1;
#define TFR(r) { x0 += x1; x1 = (x1<<r)|(x1>>(32-r)); x1 ^= x0; }
  TFR(13) TFR(15) TFR(26) TFR(6)   x0 += k1; x1 += k2 + 1u;
  TFR(17) TFR(29) TFR(16) TFR(24)  x0 += k2; x1 += k0 + 2u;
  TFR(13) TFR(15) TFR(26) TFR(6)   x0 += k0; x1 += k1 + 3u;
  TFR(17) TFR(29) TFR(16) TFR(24)  x0 += k1; x1 += k2 + 4u;
  TFR(13) TFR(15) TFR(26) TFR(6)   x0 += k2; x1 += k0 + 5u;
#undef TFR
  o0 = x0; o1 = x1;
}
// partitionable random_bits (32-bit): bits[i] = x0 ^ x1 of counter (0, i)
__device__ __forceinline__ u32 foldb(u32 k0, u32 k1, u32 i){
  u32 a,b; tf2x32(k0,k1,0u,i,a,b); return a^b;
}
__device__ __forceinline__ float b2u(u32 bits){
  union{u32 i;float f;}c; c.i = (bits>>9) | 0x3f800000u; return c.f - 1.0f;
}
// XLA ErfInv32 (Giles)
__device__ __forceinline__ float erfinv_f(float x){
  float w = -log1pf(-x*x);
  float p;
  if (w < 5.0f){
    w -= 2.5f;
    p = 2.81022636e-08f;
    p = fmaf(p,w, 3.43273939e-07f);
    p = fmaf(p,w,-3.5233877e-06f);
    p = fmaf(p,w,-4.39150654e-06f);
    p = fmaf(p,w, 0.00021858087f);
    p = fmaf(p,w,-0.00125372503f);
    p = fmaf(p,w,-0.00417768164f);
    p = fmaf(p,w, 0.246640727f);
    p = fmaf(p,w, 1.50140941f);
  } else {
    w = sqrtf(w) - 3.0f;
    p = -0.000200214257f;
    p = fmaf(p,w, 0.000100950558f);
    p = fmaf(p,w, 0.00134934322f);
    p = fmaf(p,w,-0.00367342844f);
    p = fmaf(p,w, 0.00573950773f);
    p = fmaf(p,w,-0.0076224613f);
    p = fmaf(p,w, 0.00943887047f);
    p = fmaf(p,w, 1.00167406f);
    p = fmaf(p,w, 2.83297682f);
  }
  return p*x;
}
__device__ __forceinline__ float sigm(float x){ return 1.0f/(1.0f+expf(-x)); }
__device__ __forceinline__ float rl(float x, int l){
  return __int_as_float(__builtin_amdgcn_readlane(__float_as_int(x), l));
}
__device__ __forceinline__ float wred(float x){
  #pragma unroll
  for (int m=1; m<64; m<<=1) x += __shfl_xor(x, m, 64);
  return x;
}

// Single-row GRU mat-vec, REGISTER weights (lane j = output row j per gate).
#define MATVEC1R(Wr, Wz, Wn, xv, ar, az, an)                                   \
  _Pragma("unroll")                                                            \
  for (int k4 = 0; k4 < 16; k4++){                                             \
    float4 wr = Wr[k4];                                                        \
    float4 wz = Wz[k4];                                                        \
    float4 wn = Wn[k4];                                                        \
    float x0 = rl(xv, 4*k4), x1 = rl(xv, 4*k4+1), x2 = rl(xv, 4*k4+2), x3 = rl(xv, 4*k4+3); \
    ar = fmaf(wr.x,x0,ar); ar = fmaf(wr.y,x1,ar); ar = fmaf(wr.z,x2,ar); ar = fmaf(wr.w,x3,ar); \
    az = fmaf(wz.x,x0,az); az = fmaf(wz.y,x1,az); az = fmaf(wz.z,x2,az); az = fmaf(wz.w,x3,az); \
    an = fmaf(wn.x,x0,an); an = fmaf(wn.y,x1,an); an = fmaf(wn.z,x2,an); an = fmaf(wn.w,x3,an); \
  }

// Single-row GRU mat-vec, LDS weights (layout w[k4*192 + gate*64 + j]).
#define MATVEC1L(W, xv, ar, az, an)                                            \
  _Pragma("unroll 2")                                                          \
  for (int k4 = 0; k4 < 16; k4++){                                             \
    float4 wr = W[k4*192 + j];                                                 \
    float4 wz = W[k4*192 + 64 + j];                                            \
    float4 wn = W[k4*192 + 128 + j];                                           \
    float x0 = rl(xv, 4*k4), x1 = rl(xv, 4*k4+1), x2 = rl(xv, 4*k4+2), x3 = rl(xv, 4*k4+3); \
    ar = fmaf(wr.x,x0,ar); ar = fmaf(wr.y,x1,ar); ar = fmaf(wr.z,x2,ar); ar = fmaf(wr.w,x3,ar); \
    az = fmaf(wz.x,x0,az); az = fmaf(wz.y,x1,az); az = fmaf(wz.z,x2,az); az = fmaf(wz.w,x3,az); \
    an = fmaf(wn.x,x0,an); an = fmaf(wn.y,x1,an); an = fmaf(wn.z,x2,an); an = fmaf(wn.w,x3,an); \
  }

#define LOAD_REG_W(G, Ar, Az, An)                                              \
  _Pragma("unroll")                                                            \
  for (int k4 = 0; k4 < 16; k4++){                                             \
    Ar[k4] = G[(j)*16 + k4];                                                   \
    Az[k4] = G[(64 + j)*16 + k4];                                              \
    An[k4] = G[(128 + j)*16 + k4];                                             \
  }

// PIN (enc only): keep weights register/AGPR-resident (neutral in dec, keep enc).
#define PIN4(v) asm volatile("" : "+v"(v.x), "+v"(v.y), "+v"(v.z), "+v"(v.w))
#define PIN_W(Ar, Az, An)                                                      \
  _Pragma("unroll")                                                            \
  for (int k4 = 0; k4 < 16; k4++){ PIN4(Ar[k4]); PIN4(Az[k4]); PIN4(An[k4]); }

// =====================================================================
// Encoder: unchanged from round 9 (at structural LDS floor, ~1.06 ms).
// =====================================================================
__global__ __launch_bounds__(NTHR, 2) void enc_kernel(
    const int* __restrict__ tokens, const float* __restrict__ emb,
    const float* __restrict__ Wih0, const float* __restrict__ Whh0,
    const float* __restrict__ bih0, const float* __restrict__ bhh0,
    const float* __restrict__ Wih1, const float* __restrict__ Whh1,
    const float* __restrict__ bih1, const float* __restrict__ bhh1,
    const float* __restrict__ muW, const float* __restrict__ mub,
    const float* __restrict__ vaW, const float* __restrict__ vab,
    const float* __restrict__ pW,  const float* __restrict__ pb,
    float* __restrict__ out, float* __restrict__ hz_ws)
{
  __shared__ float4 wi1[16*192];  // enc_Wih1
  __shared__ float4 wh1[16*192];  // enc_Whh1
  __shared__ float tokT[VV*192];  // input-gate table (incl. bih0) per vocab token

  const int tid = threadIdx.x;
  const int b0  = blockIdx.x * 8;
  const int j   = tid & 63;
  const int wv  = tid >> 6;
  const int row = b0 + wv;

  for (int i4 = tid; i4 < 3072; i4 += NTHR){
    int g = i4 >> 4, k4 = i4 & 15;
    wi1[k4*192 + g] = ((const float4*)Wih1)[i4];
    wh1[k4*192 + g] = ((const float4*)Whh1)[i4];
  }
  if (tid < 192){
    #pragma unroll
    for (int v = 0; v < VV; v++){
      float acc = 0.0f;
      #pragma unroll
      for (int e = 0; e < 8; e++) acc = fmaf(emb[v*8+e], Wih0[tid*8+e], acc);
      tokT[v*192 + tid] = acc + bih0[tid];
    }
  }
  for (int i = tid; i < 8*SS; i += NTHR){
    int rr = i >> 8, tq = i & 255;
    out[TOK_OFF + (b0+rr)*SS + tq] = (float)tokens[(b0+rr)*SS + tq];
  }

  float4 w0r[16], w0z[16], w0n[16];
  {
    const float4* G0 = (const float4*)Whh0;
    LOAD_REG_W(G0, w0r, w0z, w0n)
    PIN_W(w0r, w0z, w0n)
  }
  __syncthreads();

  const float bhr0 = bhh0[j], bhz0 = bhh0[64+j], bhn0 = bhh0[128+j];
  const float bir1 = bih1[j], biz1 = bih1[64+j], bin1 = bih1[128+j];
  const float bhr1 = bhh1[j], bhz1 = bhh1[64+j], bhn1 = bhh1[128+j];

  float h0 = 0.0f, h1 = 0.0f;
  const int tR = row*SS;

  for (int t = 0; t < SS; t++){
    // LICM fence (round-3: hoist -> spill -> 13.3 GB HBM refill traffic)
    asm volatile("" ::: "memory");
    int k = tokens[tR + t];
    float ar=0, az=0, an=0;
    MATVEC1R(w0r, w0z, w0n, h0, ar, az, an)
    {
      float ir = tokT[k*192+j], iz = tokT[k*192+64+j], ig = tokT[k*192+128+j];
      float rg = sigm(ir + ar + bhr0);
      float zg = sigm(iz + az + bhz0);
      float ng = tanhf(ig + rg*(an + bhn0));
      h0 = (1.0f - zg)*ng + zg*h0;
    }
    float air=0, aiz=0, ain=0, ahr=0, ahz=0, ahn=0;
    MATVEC1L(wi1, h0, air, aiz, ain)
    MATVEC1L(wh1, h1, ahr, ahz, ahn)
    {
      float rg = sigm(air + bir1 + ahr + bhr1);
      float zg = sigm(aiz + biz1 + ahz + bhz1);
      float ng = tanhf(ain + bin1 + rg*(ahn + bhn1));
      h1 = (1.0f - zg)*ng + zg*h1;
    }
  }

  const float LO_ = -0.99999994f;   // nextafter(-1, 0) in f32
  {
    float hv = h1;
    int gb = row;
    float mu0,mu1,mu2, lv0,lv1,lv2;
    { float pm = muW[0*64+j]*hv; pm = wred(pm); mu0 = pm + mub[0];
      float pv = vaW[0*64+j]*hv; pv = wred(pv); lv0 = pv + vab[0]; }
    { float pm = muW[1*64+j]*hv; pm = wred(pm); mu1 = pm + mub[1];
      float pv = vaW[1*64+j]*hv; pv = wred(pv); lv1 = pv + vab[1]; }
    { float pm = muW[2*64+j]*hv; pm = wred(pm); mu2 = pm + mub[2];
      float pv = vaW[2*64+j]*hv; pv = wred(pv); lv2 = pv + vab[2]; }
    if (j < 3){
      float mv  = (j==0)?mu0:(j==1)?mu1:mu2;
      float lvv = (j==0)?lv0:(j==1)?lv1:lv2;
      out[MU_OFF + gb*LATD + j] = mv;
      out[LV_OFF + gb*LATD + j] = lvv;
    }
    float z0,z1,z2;
    #pragma unroll
    for (int l = 0; l < 3; l++){
      u32 bits = foldb(0u, 1u, (u32)(gb*LATD + l));
      float u01 = b2u(bits);
      float uu = u01 * 2.0f;      // (hi - lo) rounds to 2.0f
      uu = uu + LO_;
      uu = fmaxf(LO_, uu);
      float ep = 1.41421354f * erfinv_f(uu);
      float lvv = (l==0)?lv0:(l==1)?lv1:lv2;
      float mvv = (l==0)?mu0:(l==1)?mu1:mu2;
      float zv = ep * expf(0.5f*lvv) + mvv;
      if (l==0) z0 = zv; else if (l==1) z1 = zv; else z2 = zv;
    }
    float hzj = pW[j*3+0]*z0;
    hzj += pW[j*3+1]*z1;
    hzj += pW[j*3+2]*z2;
    hzj += pb[j];
    hz_ws[gb*HH + j] = hzj;
  }
}

// =====================================================================
// Decoder: autoregressive; 8 waves/block, wave = 1 row.
//  - gumbels for all (t,row,v) precomputed into LDS (data-independent)
//  - decT held in 18 per-lane registers (6-way uniform select by token)
//  - segmented head reduction: masks {1,2} per logit, select, masks
//    {4,8,16,32} -- tree-identical to wred, 12 shfl instead of 24.
// =====================================================================
__global__ __launch_bounds__(NTHR, 2) void dec_kernel(
    const float* __restrict__ demb,
    const float* __restrict__ Wih0, const float* __restrict__ Whh0,
    const float* __restrict__ bih0, const float* __restrict__ bhh0,
    const float* __restrict__ Wih1, const float* __restrict__ Whh1,
    const float* __restrict__ bih1, const float* __restrict__ bhh1,
    const float* __restrict__ headW, const float* __restrict__ headb,
    const float* __restrict__ hz_ws, float* __restrict__ out)
{
  __shared__ float4 wi1[16*192];  // dec_Wih1 (48 KB)
  __shared__ float4 wh1[16*192];  // dec_Whh1 (48 KB)
  __shared__ float decT[6*192];   // input-gate table (incl. bih0) per token
  __shared__ float gum[SS*32];    // gumbel noise: [t][row-in-block][v] (32 KB)

  const int tid = threadIdx.x;
  const int b0  = blockIdx.x * 8;
  const int j   = tid & 63;
  const int wv  = tid >> 6;
  const int row = b0 + wv;
  const float TINY = 1.17549435e-38f;

  for (int i4 = tid; i4 < 3072; i4 += NTHR){
    int g = i4 >> 4, k4 = i4 & 15;
    wi1[k4*192 + g] = ((const float4*)Wih1)[i4];
    wh1[k4*192 + g] = ((const float4*)Whh1)[i4];
  }
  if (tid < 192){
    #pragma unroll
    for (int v = 0; v < 6; v++){
      float acc = 0.0f;
      #pragma unroll 8
      for (int k = 0; k < 64; k++) acc = fmaf(demb[v*64+k], Wih0[tid*64+k], acc);
      decT[v*192 + tid] = acc + bih0[tid];
    }
  }
  // precompute gumbels: key_t = split(key(2))[t], bits = foldb(key_t, row*V+v)
  for (int idx = tid; idx < SS*32; idx += NTHR){
    int t  = idx >> 5;
    int rv = idx & 31;                 // r*4+v
    u32 a,b; tf2x32(0u, 2u, 0u, (u32)t, a, b);
    u32 bits = foldb(a, b, (u32)((b0 + (rv>>2))*VV + (rv&3)));
    float u01 = b2u(bits);
    float u = fmaxf(TINY, u01 + TINY); // scale (1 - tiny) rounds to 1.0f
    gum[idx] = -logf(-logf(u));
  }

  float4 w0r[16], w0z[16], w0n[16];
  {
    const float4* G0 = (const float4*)Whh0;
    LOAD_REG_W(G0, w0r, w0z, w0n)   // no PIN: L1 streaming (round-7 baseline)
  }
  __syncthreads();

  // decT -> 18 per-lane registers
  float dTr[6], dTz[6], dTn[6];
  #pragma unroll
  for (int v = 0; v < 6; v++){
    dTr[v] = decT[v*192 + j];
    dTz[v] = decT[v*192 + 64 + j];
    dTn[v] = decT[v*192 + 128 + j];
  }

  const float bhr0 = bhh0[j], bhz0 = bhh0[64+j], bhn0 = bhh0[128+j];
  const float bir1 = bih1[j], biz1 = bih1[64+j], bin1 = bih1[128+j];
  const float bhr1 = bhh1[j], bhz1 = bhh1[64+j], bhn1 = bhh1[128+j];
  const float hw0 = headW[0*64+j], hw1 = headW[1*64+j], hw2 = headW[2*64+j], hw3 = headW[3*64+j];
  const int vv = j & 3;
  const float hbv = (vv==0)?headb[0]:(vv==1)?headb[1]:(vv==2)?headb[2]:headb[3];

  float h0 = hz_ws[row*HH + j];
  float h1 = h0;
  int tk = 4;                     // START token

  for (int t = 0; t < SS; t++){
    asm volatile("" ::: "memory");   // LICM fence (see enc_kernel comment)
    float gmb = gum[t*32 + (wv<<2) + vv];   // token-independent: hoists early
    // ---- layer 0 ----
    float ar=0, az=0, an=0;
    MATVEC1R(w0r, w0z, w0n, h0, ar, az, an)
    {
      float ir = (tk==0)?dTr[0]:(tk==1)?dTr[1]:(tk==2)?dTr[2]:(tk==3)?dTr[3]:(tk==4)?dTr[4]:dTr[5];
      float iz = (tk==0)?dTz[0]:(tk==1)?dTz[1]:(tk==2)?dTz[2]:(tk==3)?dTz[3]:(tk==4)?dTz[4]:dTz[5];
      float ig = (tk==0)?dTn[0]:(tk==1)?dTn[1]:(tk==2)?dTn[2]:(tk==3)?dTn[3]:(tk==4)?dTn[4]:dTn[5];
      float rg = sigm(ir + ar + bhr0);
      float zg = sigm(iz + az + bhz0);
      float ng = tanhf(ig + rg*(an + bhn0));
      h0 = (1.0f - zg)*ng + zg*h0;
    }
    // ---- layer 1 (both matrices from LDS) ----
    float air=0, aiz=0, ain=0, ahr=0, ahz=0, ahn=0;
    MATVEC1L(wi1, h0, air, aiz, ain)
    MATVEC1L(wh1, h1, ahr, ahz, ahn)
    {
      float rg = sigm(air + bir1 + ahr + bhr1);
      float zg = sigm(aiz + biz1 + ahz + bhz1);
      float ng = tanhf(ain + bin1 + rg*(ahn + bhn1));
      h1 = (1.0f - zg)*ng + zg*h1;
    }
    // ---- head logits: segmented reduction (tree-identical to wred) ----
    float a0 = hw0*h1, a1 = hw1*h1, a2 = hw2*h1, a3 = hw3*h1;
    a0 += __shfl_xor(a0, 1, 64); a0 += __shfl_xor(a0, 2, 64);
    a1 += __shfl_xor(a1, 1, 64); a1 += __shfl_xor(a1, 2, 64);
    a2 += __shfl_xor(a2, 1, 64); a2 += __shfl_xor(a2, 2, 64);
    a3 += __shfl_xor(a3, 1, 64); a3 += __shfl_xor(a3, 2, 64);
    float s = (vv==0)?a0:(vv==1)?a1:(vv==2)?a2:a3;
    s += __shfl_xor(s, 4, 64);
    s += __shfl_xor(s, 8, 64);
    s += __shfl_xor(s, 16, 64);
    s += __shfl_xor(s, 32, 64);
    float lg = s + hbv;              // lane j holds logit (j&3)
    float prt = lg + gmb;
    // softmax over quad
    float mx = lg;
    mx = fmaxf(mx, __shfl_xor(mx, 1, 64));
    mx = fmaxf(mx, __shfl_xor(mx, 2, 64));
    float e = expf(lg - mx);
    float se = e;
    se += __shfl_xor(se, 1, 64);
    se += __shfl_xor(se, 2, 64);
    float prob = e / se;
    // argmax over quad (first-index tie-break)
    float bp = prt; int bv = vv;
    { float o = __shfl_xor(bp, 1, 64); int ov = __shfl_xor(bv, 1, 64);
      if (o > bp || (o == bp && ov < bv)){ bp = o; bv = ov; } }
    { float o = __shfl_xor(bp, 2, 64); int ov = __shfl_xor(bv, 2, 64);
      if (o > bp || (o == bp && ov < bv)){ bp = o; bv = ov; } }
    if (j < 4) out[(size_t)row*SS*VV + (size_t)t*VV + vv] = prob;
    tk = __builtin_amdgcn_readlane(bv, 0);
  }
}

extern "C" void kernel_launch(void* const* d_in, const int* in_sizes, int n_in,
                              void* d_out, int out_size, void* d_ws, size_t ws_size,
                              hipStream_t stream){
  const int*   tokens = (const int*)d_in[0];
  const float* emb    = (const float*)d_in[1];
  const float* eWih0  = (const float*)d_in[2];  const float* eWhh0 = (const float*)d_in[3];
  const float* ebih0  = (const float*)d_in[4];  const float* ebhh0 = (const float*)d_in[5];
  const float* eWih1  = (const float*)d_in[6];  const float* eWhh1 = (const float*)d_in[7];
  const float* ebih1  = (const float*)d_in[8];  const float* ebhh1 = (const float*)d_in[9];
  const float* muW    = (const float*)d_in[10]; const float* mub   = (const float*)d_in[11];
  const float* vaW    = (const float*)d_in[12]; const float* vab   = (const float*)d_in[13];
  const float* demb   = (const float*)d_in[14];
  const float* pW     = (const float*)d_in[15]; const float* pb    = (const float*)d_in[16];
  const float* dWih0  = (const float*)d_in[17]; const float* dWhh0 = (const float*)d_in[18];
  const float* dbih0  = (const float*)d_in[19]; const float* dbhh0 = (const float*)d_in[20];
  const float* dWih1  = (const float*)d_in[21]; const float* dWhh1 = (const float*)d_in[22];
  const float* dbih1  = (const float*)d_in[23]; const float* dbhh1 = (const float*)d_in[24];
  const float* hWp    = (const float*)d_in[25]; const float* hbp   = (const float*)d_in[26];
  float* out = (float*)d_out;
  float* hz = (float*)d_ws;   // B*H fp32 = 512 KB scratch

  enc_kernel<<<NB/8, NTHR, 0, stream>>>(tokens, emb,
      eWih0, eWhh0, ebih0, ebhh0, eWih1, eWhh1, ebih1, ebhh1,
      muW, mub, vaW, vab, pW, pb, out, hz);
  dec_kernel<<<NB/8, NTHR, 0, stream>>>(demb,
      dWih0, dWhh0, dbih0, dbhh0, dWih1, dWhh1, dbih1, dbhh1,
      hWp, hbp, hz, out);
}

// Round 11
// 2635.262 us; speedup vs baseline: 1.0172x; 1.0172x over previous
//
#include <hip/hip_runtime.h>
#include <stdint.h>

typedef unsigned int u32;
typedef unsigned short u16;

#define NB   2048
#define SS   256
#define HH   64
#define VV   4
#define LATD 3
#define NTHR 512   // 8 waves, wave = 1 batch row, 256 blocks = 1 block/CU, 2 waves/SIMD

// float-element offsets in d_out: recons [B,S,1,V], tokens [B,S], mu, log_var
#define TOK_OFF (NB*SS*VV)
#define MU_OFF  (TOK_OFF + NB*SS)
#define LV_OFF  (MU_OFF + NB*LATD)

// ---------- JAX threefry2x32 (20 rounds, explicit) ----------
__device__ __forceinline__ void tf2x32(u32 k0, u32 k1, u32 x0, u32 x1, u32& o0, u32& o1){
  u32 k2 = k0 ^ k1 ^ 0x1BD11BDAu;
  x0 += k0; x1 += k1;
#define TFR(r) { x0 += x1; x1 = (x1<<r)|(x1>>(32-r)); x1 ^= x0; }
  TFR(13) TFR(15) TFR(26) TFR(6)   x0 += k1; x1 += k2 + 1u;
  TFR(17) TFR(29) TFR(16) TFR(24)  x0 += k2; x1 += k0 + 2u;
  TFR(13) TFR(15) TFR(26) TFR(6)   x0 += k0; x1 += k1 + 3u;
  TFR(17) TFR(29) TFR(16) TFR(24)  x0 += k1; x1 += k2 + 4u;
  TFR(13) TFR(15) TFR(26) TFR(6)   x0 += k2; x1 += k0 + 5u;
#undef TFR
  o0 = x0; o1 = x1;
}
// partitionable random_bits (32-bit): bits[i] = x0 ^ x1 of counter (0, i)
__device__ __forceinline__ u32 foldb(u32 k0, u32 k1, u32 i){
  u32 a,b; tf2x32(k0,k1,0u,i,a,b); return a^b;
}
__device__ __forceinline__ float b2u(u32 bits){
  union{u32 i;float f;}c; c.i = (bits>>9) | 0x3f800000u; return c.f - 1.0f;
}
// XLA ErfInv32 (Giles)
__device__ __forceinline__ float erfinv_f(float x){
  float w = -log1pf(-x*x);
  float p;
  if (w < 5.0f){
    w -= 2.5f;
    p = 2.81022636e-08f;
    p = fmaf(p,w, 3.43273939e-07f);
    p = fmaf(p,w,-3.5233877e-06f);
    p = fmaf(p,w,-4.39150654e-06f);
    p = fmaf(p,w, 0.00021858087f);
    p = fmaf(p,w,-0.00125372503f);
    p = fmaf(p,w,-0.00417768164f);
    p = fmaf(p,w, 0.246640727f);
    p = fmaf(p,w, 1.50140941f);
  } else {
    w = sqrtf(w) - 3.0f;
    p = -0.000200214257f;
    p = fmaf(p,w, 0.000100950558f);
    p = fmaf(p,w, 0.00134934322f);
    p = fmaf(p,w,-0.00367342844f);
    p = fmaf(p,w, 0.00573950773f);
    p = fmaf(p,w,-0.0076224613f);
    p = fmaf(p,w, 0.00943887047f);
    p = fmaf(p,w, 1.00167406f);
    p = fmaf(p,w, 2.83297682f);
  }
  return p*x;
}
__device__ __forceinline__ float sigm(float x){ return 1.0f/(1.0f+expf(-x)); }
__device__ __forceinline__ float rl(float x, int l){
  return __int_as_float(__builtin_amdgcn_readlane(__float_as_int(x), l));
}
__device__ __forceinline__ float wred(float x){
  #pragma unroll
  for (int m=1; m<64; m<<=1) x += __shfl_xor(x, m, 64);
  return x;
}

// Single-row GRU mat-vec, REGISTER weights (lane j = output row j per gate).
#define MATVEC1R(Wr, Wz, Wn, xv, ar, az, an)                                   \
  _Pragma("unroll")                                                            \
  for (int k4 = 0; k4 < 16; k4++){                                             \
    float4 wr = Wr[k4];                                                        \
    float4 wz = Wz[k4];                                                        \
    float4 wn = Wn[k4];                                                        \
    float x0 = rl(xv, 4*k4), x1 = rl(xv, 4*k4+1), x2 = rl(xv, 4*k4+2), x3 = rl(xv, 4*k4+3); \
    ar = fmaf(wr.x,x0,ar); ar = fmaf(wr.y,x1,ar); ar = fmaf(wr.z,x2,ar); ar = fmaf(wr.w,x3,ar); \
    az = fmaf(wz.x,x0,az); az = fmaf(wz.y,x1,az); az = fmaf(wz.z,x2,az); az = fmaf(wz.w,x3,az); \
    an = fmaf(wn.x,x0,an); an = fmaf(wn.y,x1,an); an = fmaf(wn.z,x2,an); an = fmaf(wn.w,x3,an); \
  }

// Single-row GRU mat-vec, LDS weights (layout w[k4*192 + gate*64 + j]).
#define MATVEC1L(W, xv, ar, az, an)                                            \
  _Pragma("unroll 2")                                                          \
  for (int k4 = 0; k4 < 16; k4++){                                             \
    float4 wr = W[k4*192 + j];                                                 \
    float4 wz = W[k4*192 + 64 + j];                                            \
    float4 wn = W[k4*192 + 128 + j];                                           \
    float x0 = rl(xv, 4*k4), x1 = rl(xv, 4*k4+1), x2 = rl(xv, 4*k4+2), x3 = rl(xv, 4*k4+3); \
    ar = fmaf(wr.x,x0,ar); ar = fmaf(wr.y,x1,ar); ar = fmaf(wr.z,x2,ar); ar = fmaf(wr.w,x3,ar); \
    az = fmaf(wz.x,x0,az); az = fmaf(wz.y,x1,az); az = fmaf(wz.z,x2,az); az = fmaf(wz.w,x3,az); \
    an = fmaf(wn.x,x0,an); an = fmaf(wn.y,x1,an); an = fmaf(wn.z,x2,an); an = fmaf(wn.w,x3,an); \
  }

#define LOAD_REG_W(G, Ar, Az, An)                                              \
  _Pragma("unroll")                                                            \
  for (int k4 = 0; k4 < 16; k4++){                                             \
    Ar[k4] = G[(j)*16 + k4];                                                   \
    Az[k4] = G[(64 + j)*16 + k4];                                              \
    An[k4] = G[(128 + j)*16 + k4];                                             \
  }

// PIN (enc only): measured best enc config (R9, ~1068 us). Neutral in dec.
#define PIN4(v) asm volatile("" : "+v"(v.x), "+v"(v.y), "+v"(v.z), "+v"(v.w))
#define PIN_W(Ar, Az, An)                                                      \
  _Pragma("unroll")                                                            \
  for (int k4 = 0; k4 < 16; k4++){ PIN4(Ar[k4]); PIN4(Az[k4]); PIN4(An[k4]); }

// =====================================================================
// Encoder: R9 config (measured ~1068 us; ~92% of LDS-pipe floor).
// =====================================================================
__global__ __launch_bounds__(NTHR, 2) void enc_kernel(
    const int* __restrict__ tokens, const float* __restrict__ emb,
    const float* __restrict__ Wih0, const float* __restrict__ Whh0,
    const float* __restrict__ bih0, const float* __restrict__ bhh0,
    const float* __restrict__ Wih1, const float* __restrict__ Whh1,
    const float* __restrict__ bih1, const float* __restrict__ bhh1,
    const float* __restrict__ muW, const float* __restrict__ mub,
    const float* __restrict__ vaW, const float* __restrict__ vab,
    const float* __restrict__ pW,  const float* __restrict__ pb,
    float* __restrict__ out, float* __restrict__ hz_ws)
{
  __shared__ float4 wi1[16*192];  // enc_Wih1
  __shared__ float4 wh1[16*192];  // enc_Whh1
  __shared__ float tokT[VV*192];  // input-gate table (incl. bih0) per vocab token

  const int tid = threadIdx.x;
  const int b0  = blockIdx.x * 8;
  const int j   = tid & 63;
  const int wv  = tid >> 6;
  const int row = b0 + wv;

  for (int i4 = tid; i4 < 3072; i4 += NTHR){
    int g = i4 >> 4, k4 = i4 & 15;
    wi1[k4*192 + g] = ((const float4*)Wih1)[i4];
    wh1[k4*192 + g] = ((const float4*)Whh1)[i4];
  }
  if (tid < 192){
    #pragma unroll
    for (int v = 0; v < VV; v++){
      float acc = 0.0f;
      #pragma unroll
      for (int e = 0; e < 8; e++) acc = fmaf(emb[v*8+e], Wih0[tid*8+e], acc);
      tokT[v*192 + tid] = acc + bih0[tid];
    }
  }
  for (int i = tid; i < 8*SS; i += NTHR){
    int rr = i >> 8, tq = i & 255;
    out[TOK_OFF + (b0+rr)*SS + tq] = (float)tokens[(b0+rr)*SS + tq];
  }

  float4 w0r[16], w0z[16], w0n[16];
  {
    const float4* G0 = (const float4*)Whh0;
    LOAD_REG_W(G0, w0r, w0z, w0n)
    PIN_W(w0r, w0z, w0n)
  }
  __syncthreads();

  const float bhr0 = bhh0[j], bhz0 = bhh0[64+j], bhn0 = bhh0[128+j];
  const float bir1 = bih1[j], biz1 = bih1[64+j], bin1 = bih1[128+j];
  const float bhr1 = bhh1[j], bhz1 = bhh1[64+j], bhn1 = bhh1[128+j];

  float h0 = 0.0f, h1 = 0.0f;
  const int tR = row*SS;

  for (int t = 0; t < SS; t++){
    // LICM fence (round-3: hoist -> spill -> 13.3 GB HBM refill traffic)
    asm volatile("" ::: "memory");
    int k = tokens[tR + t];
    float ar=0, az=0, an=0;
    MATVEC1R(w0r, w0z, w0n, h0, ar, az, an)
    {
      float ir = tokT[k*192+j], iz = tokT[k*192+64+j], ig = tokT[k*192+128+j];
      float rg = sigm(ir + ar + bhr0);
      float zg = sigm(iz + az + bhz0);
      float ng = tanhf(ig + rg*(an + bhn0));
      h0 = (1.0f - zg)*ng + zg*h0;
    }
    float air=0, aiz=0, ain=0, ahr=0, ahz=0, ahn=0;
    MATVEC1L(wi1, h0, air, aiz, ain)
    MATVEC1L(wh1, h1, ahr, ahz, ahn)
    {
      float rg = sigm(air + bir1 + ahr + bhr1);
      float zg = sigm(aiz + biz1 + ahz + bhz1);
      float ng = tanhf(ain + bin1 + rg*(ahn + bhn1));
      h1 = (1.0f - zg)*ng + zg*h1;
    }
  }

  const float LO_ = -0.99999994f;   // nextafter(-1, 0) in f32
  {
    float hv = h1;
    int gb = row;
    float mu0,mu1,mu2, lv0,lv1,lv2;
    { float pm = muW[0*64+j]*hv; pm = wred(pm); mu0 = pm + mub[0];
      float pv = vaW[0*64+j]*hv; pv = wred(pv); lv0 = pv + vab[0]; }
    { float pm = muW[1*64+j]*hv; pm = wred(pm); mu1 = pm + mub[1];
      float pv = vaW[1*64+j]*hv; pv = wred(pv); lv1 = pv + vab[1]; }
    { float pm = muW[2*64+j]*hv; pm = wred(pm); mu2 = pm + mub[2];
      float pv = vaW[2*64+j]*hv; pv = wred(pv); lv2 = pv + vab[2]; }
    if (j < 3){
      float mv  = (j==0)?mu0:(j==1)?mu1:mu2;
      float lvv = (j==0)?lv0:(j==1)?lv1:lv2;
      out[MU_OFF + gb*LATD + j] = mv;
      out[LV_OFF + gb*LATD + j] = lvv;
    }
    float z0,z1,z2;
    #pragma unroll
    for (int l = 0; l < 3; l++){
      u32 bits = foldb(0u, 1u, (u32)(gb*LATD + l));
      float u01 = b2u(bits);
      float uu = u01 * 2.0f;      // (hi - lo) rounds to 2.0f
      uu = uu + LO_;
      uu = fmaxf(LO_, uu);
      float ep = 1.41421354f * erfinv_f(uu);
      float lvv = (l==0)?lv0:(l==1)?lv1:lv2;
      float mvv = (l==0)?mu0:(l==1)?mu1:mu2;
      float zv = ep * expf(0.5f*lvv) + mvv;
      if (l==0) z0 = zv; else if (l==1) z1 = zv; else z2 = zv;
    }
    float hzj = pW[j*3+0]*z0;
    hzj += pW[j*3+1]*z1;
    hzj += pW[j*3+2]*z2;
    hzj += pb[j];
    hz_ws[gb*HH + j] = hzj;
  }
}

// =====================================================================
// Decoder: exact revert to R7 config (measured best, 1554 us):
// no PIN (L1 streaming for Whh0), decT from LDS, inline threefry+gumbel,
// full-wave wred head reductions, quad softmax/argmax.
// =====================================================================
__global__ __launch_bounds__(NTHR, 2) void dec_kernel(
    const float* __restrict__ demb,
    const float* __restrict__ Wih0, const float* __restrict__ Whh0,
    const float* __restrict__ bih0, const float* __restrict__ bhh0,
    const float* __restrict__ Wih1, const float* __restrict__ Whh1,
    const float* __restrict__ bih1, const float* __restrict__ bhh1,
    const float* __restrict__ headW, const float* __restrict__ headb,
    const float* __restrict__ hz_ws, float* __restrict__ out)
{
  __shared__ float4 wi1[16*192];  // dec_Wih1
  __shared__ float4 wh1[16*192];  // dec_Whh1
  __shared__ float decT[6*192];   // input-gate table (incl. bih0) per token
  __shared__ u32 sk0[SS], sk1[SS];

  const int tid = threadIdx.x;
  const int b0  = blockIdx.x * 8;
  const int j   = tid & 63;
  const int wv  = tid >> 6;
  const int row = b0 + wv;

  for (int i4 = tid; i4 < 3072; i4 += NTHR){
    int g = i4 >> 4, k4 = i4 & 15;
    wi1[k4*192 + g] = ((const float4*)Wih1)[i4];
    wh1[k4*192 + g] = ((const float4*)Whh1)[i4];
  }
  if (tid < 192){
    #pragma unroll
    for (int v = 0; v < 6; v++){
      float acc = 0.0f;
      #pragma unroll 8
      for (int k = 0; k < 64; k++) acc = fmaf(demb[v*64+k], Wih0[tid*64+k], acc);
      decT[v*192 + tid] = acc + bih0[tid];
    }
  }
  // split(key(2), 256): key_t = full output pair of threefry(key2, (0, t))
  if (tid < SS){
    u32 a,b; tf2x32(0u, 2u, 0u, (u32)tid, a, b);
    sk0[tid] = a; sk1[tid] = b;
  }

  float4 w0r[16], w0z[16], w0n[16];
  {
    const float4* G0 = (const float4*)Whh0;
    LOAD_REG_W(G0, w0r, w0z, w0n)   // no PIN: L1 streaming (R7 measured best)
  }
  __syncthreads();

  const float bhr0 = bhh0[j], bhz0 = bhh0[64+j], bhn0 = bhh0[128+j];
  const float bir1 = bih1[j], biz1 = bih1[64+j], bin1 = bih1[128+j];
  const float bhr1 = bhh1[j], bhz1 = bhh1[64+j], bhn1 = bhh1[128+j];
  const float hw0 = headW[0*64+j], hw1 = headW[1*64+j], hw2 = headW[2*64+j], hw3 = headW[3*64+j];
  const float hb0 = headb[0], hb1 = headb[1], hb2 = headb[2], hb3 = headb[3];

  float h0 = hz_ws[row*HH + j];
  float h1 = h0;
  int tk = 4;                     // START token

  const int vv = j & 3;           // lane's vocab slot (quads replicate)
  const float TINY = 1.17549435e-38f;

  for (int t = 0; t < SS; t++){
    asm volatile("" ::: "memory");   // LICM fence (see enc_kernel comment)
    // ---- layer 0 ----
    float ar=0, az=0, an=0;
    MATVEC1R(w0r, w0z, w0n, h0, ar, az, an)
    {
      float ir = decT[tk*192+j], iz = decT[tk*192+64+j], ig = decT[tk*192+128+j];
      float rg = sigm(ir + ar + bhr0);
      float zg = sigm(iz + az + bhz0);
      float ng = tanhf(ig + rg*(an + bhn0));
      h0 = (1.0f - zg)*ng + zg*h0;
    }
    // ---- layer 1 (both matrices from LDS, separate unroll-2 loops) ----
    float air=0, aiz=0, ain=0, ahr=0, ahz=0, ahn=0;
    MATVEC1L(wi1, h0, air, aiz, ain)
    MATVEC1L(wh1, h1, ahr, ahz, ahn)
    {
      float rg = sigm(air + bir1 + ahr + bhr1);
      float zg = sigm(aiz + biz1 + ahz + bhz1);
      float ng = tanhf(ain + bin1 + rg*(ahn + bhn1));
      h1 = (1.0f - zg)*ng + zg*h1;
    }
    // ---- head logits (wave reductions) ----
    float l0 = wred(hw0*h1) + hb0;
    float l1 = wred(hw1*h1) + hb1;
    float l2 = wred(hw2*h1) + hb2;
    float l3 = wred(hw3*h1) + hb3;
    // ---- gumbel sample + softmax (quad-parallel, all lanes uniform) ----
    float lg = (vv==0)?l0:(vv==1)?l1:(vv==2)?l2:l3;
    u32 bits = foldb(sk0[t], sk1[t], (u32)(row*VV + vv));
    float u01 = b2u(bits);
    float u = u01 + TINY;          // scale (1 - tiny) rounds to 1.0f
    u = fmaxf(TINY, u);
    float gmb = -logf(-logf(u));
    float prt = lg + gmb;
    // softmax over quad
    float mx = lg;
    mx = fmaxf(mx, __shfl_xor(mx, 1, 64));
    mx = fmaxf(mx, __shfl_xor(mx, 2, 64));
    float e = expf(lg - mx);
    float se = e;
    se += __shfl_xor(se, 1, 64);
    se += __shfl_xor(se, 2, 64);
    float prob = e / se;
    // argmax over quad (first-index tie-break)
    float bp = prt; int bv = vv;
    { float o = __shfl_xor(bp, 1, 64); int ov = __shfl_xor(bv, 1, 64);
      if (o > bp || (o == bp && ov < bv)){ bp = o; bv = ov; } }
    { float o = __shfl_xor(bp, 2, 64); int ov = __shfl_xor(bv, 2, 64);
      if (o > bp || (o == bp && ov < bv)){ bp = o; bv = ov; } }
    if (j < 4) out[(size_t)row*SS*VV + (size_t)t*VV + vv] = prob;
    tk = __builtin_amdgcn_readlane(bv, 0);
  }
}

extern "C" void kernel_launch(void* const* d_in, const int* in_sizes, int n_in,
                              void* d_out, int out_size, void* d_ws, size_t ws_size,
                              hipStream_t stream){
  const int*   tokens = (const int*)d_in[0];
  const float* emb    = (const float*)d_in[1];
  const float* eWih0  = (const float*)d_in[2];  const float* eWhh0 = (const float*)d_in[3];
  const float* ebih0  = (const float*)d_in[4];  const float* ebhh0 = (const float*)d_in[5];
  const float* eWih1  = (const float*)d_in[6];  const float* eWhh1 = (const float*)d_in[7];
  const float* ebih1  = (const float*)d_in[8];  const float* ebhh1 = (const float*)d_in[9];
  const float* muW    = (const float*)d_in[10]; const float* mub   = (const float*)d_in[11];
  const float* vaW    = (const float*)d_in[12]; const float* vab   = (const float*)d_in[13];
  const float* demb   = (const float*)d_in[14];
  const float* pW     = (const float*)d_in[15]; const float* pb    = (const float*)d_in[16];
  const float* dWih0  = (const float*)d_in[17]; const float* dWhh0 = (const float*)d_in[18];
  const float* dbih0  = (const float*)d_in[19]; const float* dbhh0 = (const float*)d_in[20];
  const float* dWih1  = (const float*)d_in[21]; const float* dWhh1 = (const float*)d_in[22];
  const float* dbih1  = (const float*)d_in[23]; const float* dbhh1 = (const float*)d_in[24];
  const float* hWp    = (const float*)d_in[25]; const float* hbp   = (const float*)d_in[26];
  float* out = (float*)d_out;
  float* hz = (float*)d_ws;   // B*H fp32 = 512 KB scratch

  enc_kernel<<<NB/8, NTHR, 0, stream>>>(tokens, emb,
      eWih0, eWhh0, ebih0, ebhh0, eWih1, eWhh1, ebih1, ebhh1,
      muW, mub, vaW, vab, pW, pb, out, hz);
  dec_kernel<<<NB/8, NTHR, 0, stream>>>(demb,
      dWih0, dWhh0, dbih0, dbhh0, dWih1, dWhh1, dbih1, dbhh1,
      hWp, hbp, hz, out);
}